// Round 3
// baseline (328.711 us; speedup 1.0000x reference)
//
#include <hip/hip_runtime.h>

#define NN 8192
#define CC 64

typedef float f32x4 __attribute__((ext_vector_type(4)));
typedef short short8 __attribute__((ext_vector_type(8)));
typedef unsigned short u16x4 __attribute__((ext_vector_type(4)));

__device__ __forceinline__ unsigned short f2bf(float f) {
    union { float f; unsigned u; } v; v.f = f;
    return (unsigned short)((v.u + 0x7fffu + ((v.u >> 16) & 1u)) >> 16);
}
__device__ __forceinline__ float b2f(unsigned short h) {
    union { unsigned u; float f; } v; v.u = ((unsigned)h) << 16;
    return v.f;
}

// labT[c][k] = bf16(labels[k][c]); grid 512 x 256
__global__ __launch_bounds__(256)
void prep_labels(const float* __restrict__ labels, unsigned short* __restrict__ labT) {
    const int gid = blockIdx.x * 256 + threadIdx.x;   // 0 .. 131071
    const int k  = gid >> 4;
    const int c4 = (gid & 15) << 2;
    f32x4 v = *(const f32x4*)(labels + (size_t)k * CC + c4);
#pragma unroll
    for (int j = 0; j < 4; ++j)
        labT[(size_t)(c4 + j) * NN + k] = f2bf(v[j]);
}

// One block = 4 rows. Phase 1 (double-buffered loads): products -> bf16 LDS
// + row L1 sums. Then T-write, y_hat MFMA K-split across 8 waves, reduce.
template<bool USE_LABT>
__global__ __launch_bounds__(512, 4)
void lp_main(const float* __restrict__ bi, const float* __restrict__ mk,
             const float* __restrict__ labels, const unsigned short* __restrict__ labT,
             float* __restrict__ T, float* __restrict__ yhat)
{
    __shared__ unsigned short pT[4 * NN];   // 65536 B exactly
    const int t    = threadIdx.x;
    const int lane = t & 63;
    const int w    = t >> 6;
    const size_t rowbase = (size_t)blockIdx.x * 4 * NN;

    const f32x4* bp = (const f32x4*)(bi + rowbase);   // row stride 2048 (f32x4)
    const f32x4* mp = (const f32x4*)(mk + rowbase);

    f32x4 ba[4], ma[4], bb[4], mb[4];                 // double buffers
    float pl[4];
    float h0 = 0.f, h1 = 0.f, h2 = 0.f, h3 = 0.f;     // held chunk (r=3,k=3)

    // ---- phase 1: double-buffered row loads; products + row partial sums ----
#pragma unroll
    for (int k = 0; k < 4; ++k) { ba[k] = bp[t + 512 * k]; ma[k] = mp[t + 512 * k]; }

#pragma unroll
    for (int r = 0; r < 4; ++r) {
        if (r < 3) {                                  // prefetch row r+1
            const f32x4* bn = bp + (r + 1) * 2048;
            const f32x4* mn = mp + (r + 1) * 2048;
#pragma unroll
            for (int k = 0; k < 4; ++k) {
                if (r & 1) { ba[k] = bn[t + 512 * k]; ma[k] = mn[t + 512 * k]; }
                else       { bb[k] = bn[t + 512 * k]; mb[k] = mn[t + 512 * k]; }
            }
        }
        float s = 0.f;
#pragma unroll
        for (int k = 0; k < 4; ++k) {
            f32x4 B = (r & 1) ? bb[k] : ba[k];
            f32x4 M = (r & 1) ? mb[k] : ma[k];
            f32x4 p = B * M;                          // nonneg (U[0,1] products)
            s += (p[0] + p[1]) + (p[2] + p[3]);
            const int j4 = t + 512 * k;
            if (r == 3 && k == 3) { h0 = p[0]; h1 = p[1]; h2 = p[2]; h3 = p[3]; }
            else {
                u16x4 q = { f2bf(p[0]), f2bf(p[1]), f2bf(p[2]), f2bf(p[3]) };
                *(u16x4*)(pT + r * NN + (j4 << 2)) = q;
            }
        }
        pl[r] = s;
    }

    // ---- wave reduce (64 lanes) ----
#pragma unroll
    for (int r = 0; r < 4; ++r) {
        float s = pl[r];
#pragma unroll
        for (int d = 32; d >= 1; d >>= 1) s += __shfl_xor(s, d, 64);
        pl[r] = s;
    }
    // cross-wave reduce via scratch stolen from the held region (row3 tail)
    float* scr = (float*)(pT + 3 * NN + 8128);     // 128 B = 8 waves x 4 floats
    if (lane == 0) {
#pragma unroll
        for (int r = 0; r < 4; ++r) scr[w * 4 + r] = pl[r];
    }
    __syncthreads();
    float sc[4];
#pragma unroll
    for (int r = 0; r < 4; ++r) {
        float s = 0.f;
#pragma unroll
        for (int ww = 0; ww < 8; ++ww) s += scr[ww * 4 + r];
        sc[r] = 1.0f / fmaxf(s, 1e-12f);
    }
    __syncthreads();                               // scr consumed by all waves
    {   // held chunk -> LDS (needed only by the MFMA phase, after next barrier)
        const int j4 = t + 1536;
        u16x4 q = { f2bf(h0), f2bf(h1), f2bf(h2), f2bf(h3) };
        *(u16x4*)(pT + 3 * NN + (j4 << 2)) = q;
    }

    // ---- T write (held chunk straight from registers; rest from LDS) ----
#pragma unroll
    for (int r = 0; r < 4; ++r) {
        f32x4* To = (f32x4*)(T + rowbase + (size_t)r * NN);
        const float s = sc[r];
#pragma unroll
        for (int k = 0; k < 4; ++k) {
            const int j4 = t + 512 * k;
            f32x4 o;
            if (r == 3 && k == 3) {
                o = (f32x4){ h0 * s, h1 * s, h2 * s, h3 * s };
            } else {
                u16x4 q = *(const u16x4*)(pT + r * NN + (j4 << 2));
                o = (f32x4){ b2f(q[0]) * s, b2f(q[1]) * s, b2f(q[2]) * s, b2f(q[3]) * s };
            }
            __builtin_nontemporal_store(o, To + j4);
        }
    }
    __syncthreads();                               // pT fully final for MFMA

    // ---- phase 2: y_hat MFMA, K-split across all 8 waves ----
    const int c15    = lane & 15;
    const int rowsel = lane & 3;          // A rows 0..15 = dup of rows 0..3
    const int kgrp   = (lane >> 4) << 3;  // 0,8,16,24
    const int kbase  = w * (NN / 8);      // 1024 K per wave
    f32x4 acc0 = {0.f,0.f,0.f,0.f}, acc1 = acc0, acc2 = acc0, acc3 = acc0;
    const unsigned short* pA = pT + rowsel * NN + kbase + kgrp;
    if (USE_LABT) {
        const unsigned short* lb0 = labT + (size_t)(c15)      * NN + kbase + kgrp;
        const unsigned short* lb1 = labT + (size_t)(16 + c15) * NN + kbase + kgrp;
        const unsigned short* lb2 = labT + (size_t)(32 + c15) * NN + kbase + kgrp;
        const unsigned short* lb3 = labT + (size_t)(48 + c15) * NN + kbase + kgrp;
#pragma unroll 4
        for (int k0 = 0; k0 < NN / 8; k0 += 32) {
            short8 a = *(const short8*)(pA + k0);
            acc0 = __builtin_amdgcn_mfma_f32_16x16x32_bf16(a, *(const short8*)(lb0 + k0), acc0, 0, 0, 0);
            acc1 = __builtin_amdgcn_mfma_f32_16x16x32_bf16(a, *(const short8*)(lb1 + k0), acc1, 0, 0, 0);
            acc2 = __builtin_amdgcn_mfma_f32_16x16x32_bf16(a, *(const short8*)(lb2 + k0), acc2, 0, 0, 0);
            acc3 = __builtin_amdgcn_mfma_f32_16x16x32_bf16(a, *(const short8*)(lb3 + k0), acc3, 0, 0, 0);
        }
    } else {
        for (int k0 = 0; k0 < NN / 8; k0 += 32) {
            short8 a = *(const short8*)(pA + k0);
            short8 q0, q1, q2, q3;
#pragma unroll
            for (int i = 0; i < 8; ++i) {
                const size_t kr = (size_t)(kbase + k0 + kgrp + i) * CC;
                q0[i] = (short)f2bf(labels[kr + c15]);
                q1[i] = (short)f2bf(labels[kr + 16 + c15]);
                q2[i] = (short)f2bf(labels[kr + 32 + c15]);
                q3[i] = (short)f2bf(labels[kr + 48 + c15]);
            }
            acc0 = __builtin_amdgcn_mfma_f32_16x16x32_bf16(a, q0, acc0, 0, 0, 0);
            acc1 = __builtin_amdgcn_mfma_f32_16x16x32_bf16(a, q1, acc1, 0, 0, 0);
            acc2 = __builtin_amdgcn_mfma_f32_16x16x32_bf16(a, q2, acc2, 0, 0, 0);
            acc3 = __builtin_amdgcn_mfma_f32_16x16x32_bf16(a, q3, acc3, 0, 0, 0);
        }
    }
    __syncthreads();   // all waves done reading pT; safe to reuse as scratch

    // ---- per-wave partials -> LDS (8 KB at head of pT) ----
    // D layout: col = lane&15, row = (lane>>4)*4 + reg; rows 0..3 live in
    // lanes 0..15 regs 0..3.
    float* scrF = (float*)pT;
    if (lane < 16) {
#pragma unroll
        for (int i = 0; i < 4; ++i) {
            scrF[((w * 4 + 0) * 4 + i) * 16 + c15] = acc0[i];
            scrF[((w * 4 + 1) * 4 + i) * 16 + c15] = acc1[i];
            scrF[((w * 4 + 2) * 4 + i) * 16 + c15] = acc2[i];
            scrF[((w * 4 + 3) * 4 + i) * 16 + c15] = acc3[i];
        }
    }
    __syncthreads();

    // ---- final reduce over 8 waves + scale + yhat write (threads 0..255) ----
    if (t < 256) {
        const int r  = t >> 6;
        const int c  = t & 63;
        const int j  = c >> 4;
        const int cl = c & 15;
        float s = 0.f;
#pragma unroll
        for (int ww = 0; ww < 8; ++ww)
            s += scrF[((ww * 4 + j) * 4 + r) * 16 + cl];
        const float scl = (r == 0) ? sc[0] : (r == 1) ? sc[1] : (r == 2) ? sc[2] : sc[3];
        yhat[(size_t)blockIdx.x * 4 * CC + (size_t)r * CC + c] = s * scl;
    }
}

extern "C" void kernel_launch(void* const* d_in, const int* in_sizes, int n_in,
                              void* d_out, int out_size, void* d_ws, size_t ws_size,
                              hipStream_t stream) {
    (void)in_sizes; (void)n_in; (void)out_size;
    const float* labels = (const float*)d_in[2];
    const float* bi     = (const float*)d_in[4];
    const float* mask   = (const float*)d_in[5];
    float* T    = (float*)d_out;
    float* yhat = (float*)d_out + (size_t)NN * NN;
    unsigned short* labT = (unsigned short*)d_ws;

    const bool use_labt = ws_size >= (size_t)NN * CC * 2;
    if (use_labt) {
        prep_labels<<<dim3(NN * CC / 4 / 256), dim3(256), 0, stream>>>(labels, labT);
        lp_main<true><<<dim3(NN / 4), dim3(512), 0, stream>>>(bi, mask, labels, labT, T, yhat);
    } else {
        lp_main<false><<<dim3(NN / 4), dim3(512), 0, stream>>>(bi, mask, labels, labT, T, yhat);
    }
}

// Round 5
// 224.283 us; speedup vs baseline: 1.4656x; 1.4656x over previous
//
#include <hip/hip_runtime.h>

#define NN 8192
#define CC 64

typedef float f32x4 __attribute__((ext_vector_type(4)));
typedef short short8 __attribute__((ext_vector_type(8)));
typedef unsigned short u16x4 __attribute__((ext_vector_type(4)));

__device__ __forceinline__ unsigned short f2bf(float f) {
    union { float f; unsigned u; } v; v.f = f;
    return (unsigned short)((v.u + 0x7fffu + ((v.u >> 16) & 1u)) >> 16);
}
__device__ __forceinline__ float b2f(unsigned short h) {
    union { unsigned u; float f; } v; v.u = ((unsigned)h) << 16;
    return v.f;
}

// labT[c][k] = bf16(labels[k][c]); grid 512 x 256
__global__ __launch_bounds__(256)
void prep_labels(const float* __restrict__ labels, unsigned short* __restrict__ labT) {
    const int gid = blockIdx.x * 256 + threadIdx.x;   // 0 .. 131071
    const int k  = gid >> 4;
    const int c4 = (gid & 15) << 2;
    f32x4 v = *(const f32x4*)(labels + (size_t)k * CC + c4);
#pragma unroll
    for (int j = 0; j < 4; ++j)
        labT[(size_t)(c4 + j) * NN + k] = f2bf(v[j]);
}

// ---------------- K2: pure streaming normalize ----------------
// One row per 256-thread block. Read b,m (nt); f32 products in regs;
// row L1 sum; T = p*scale (f32, nt store); P = bf16(p*scale) (plain store).
__global__ __launch_bounds__(256)
void lp_stream(const float* __restrict__ bi, const float* __restrict__ mk,
               float* __restrict__ T, unsigned short* __restrict__ P)
{
    __shared__ float scr[4];
    const int t    = threadIdx.x;
    const int lane = t & 63;
    const int w    = t >> 6;
    const size_t rb = (size_t)blockIdx.x * NN;
    const f32x4* b4 = (const f32x4*)(bi + rb);
    const f32x4* m4 = (const f32x4*)(mk + rb);

    f32x4 pf[8];
    float s = 0.f;
    {
        f32x4 bv[8], mv[8];
#pragma unroll
        for (int kk = 0; kk < 8; ++kk) bv[kk] = __builtin_nontemporal_load(b4 + t + 256 * kk);
#pragma unroll
        for (int kk = 0; kk < 8; ++kk) mv[kk] = __builtin_nontemporal_load(m4 + t + 256 * kk);
#pragma unroll
        for (int kk = 0; kk < 8; ++kk) {
            pf[kk] = bv[kk] * mv[kk];               // nonneg (U[0,1] inputs)
            s += (pf[kk][0] + pf[kk][1]) + (pf[kk][2] + pf[kk][3]);
        }
    }
    // wave reduce
#pragma unroll
    for (int d = 32; d >= 1; d >>= 1) s += __shfl_xor(s, d, 64);
    if (lane == 0) scr[w] = s;
    __syncthreads();
    const float tot   = (scr[0] + scr[1]) + (scr[2] + scr[3]);
    const float scale = 1.0f / fmaxf(tot, 1e-12f);

#pragma unroll
    for (int kk = 0; kk < 8; ++kk) {
        f32x4 o = pf[kk] * scale;                   // normalized, exact f32
        __builtin_nontemporal_store(o, (f32x4*)(T + rb) + t + 256 * kk);
        u16x4 q = { f2bf(o[0]), f2bf(o[1]), f2bf(o[2]), f2bf(o[3]) };
        *((u16x4*)(P + rb) + t + 256 * kk) = q;     // normalized bf16 for lp_gemm
    }
}

// ---------------- K3: yhat = P @ labels via MFMA ----------------
// 256 blocks x 256 threads (4 waves). Block: 32 rows. wave w: row-group
// rg=w&1 (16 distinct A rows), K-half kh=w>>1 (4096). LDS reduce over kh.
__global__ __launch_bounds__(256)
void lp_gemm(const unsigned short* __restrict__ P, const unsigned short* __restrict__ labT,
             float* __restrict__ yhat)
{
    __shared__ float scrF[4][16][64];   // 16 KB
    const int t    = threadIdx.x;
    const int lane = t & 63;
    const int w    = t >> 6;
    const int rg   = w & 1;
    const int kh   = w >> 1;
    const int c15  = lane & 15;
    const int kgrp = (lane >> 4) << 3;
    const int rowbase = blockIdx.x * 32;
    const int kbase   = kh * (NN / 2);

    const unsigned short* pA  = P + (size_t)(rowbase + rg * 16 + c15) * NN + kbase + kgrp;
    const unsigned short* lb0 = labT + (size_t)(c15)      * NN + kbase + kgrp;
    const unsigned short* lb1 = labT + (size_t)(16 + c15) * NN + kbase + kgrp;
    const unsigned short* lb2 = labT + (size_t)(32 + c15) * NN + kbase + kgrp;
    const unsigned short* lb3 = labT + (size_t)(48 + c15) * NN + kbase + kgrp;

    f32x4 acc0 = {0.f,0.f,0.f,0.f}, acc1 = acc0, acc2 = acc0, acc3 = acc0;
#pragma unroll 4
    for (int k0 = 0; k0 < NN / 2; k0 += 32) {
        short8 a = *(const short8*)(pA + k0);
        acc0 = __builtin_amdgcn_mfma_f32_16x16x32_bf16(a, *(const short8*)(lb0 + k0), acc0, 0, 0, 0);
        acc1 = __builtin_amdgcn_mfma_f32_16x16x32_bf16(a, *(const short8*)(lb1 + k0), acc1, 0, 0, 0);
        acc2 = __builtin_amdgcn_mfma_f32_16x16x32_bf16(a, *(const short8*)(lb2 + k0), acc2, 0, 0, 0);
        acc3 = __builtin_amdgcn_mfma_f32_16x16x32_bf16(a, *(const short8*)(lb3 + k0), acc3, 0, 0, 0);
    }

    // D layout: col = lane&15, row(within 16) = (lane>>4)*4 + reg
#pragma unroll
    for (int i = 0; i < 4; ++i) {
        const int r15 = (lane >> 4) * 4 + i;
        scrF[w][r15][ 0 + c15] = acc0[i];
        scrF[w][r15][16 + c15] = acc1[i];
        scrF[w][r15][32 + c15] = acc2[i];
        scrF[w][r15][48 + c15] = acc3[i];
    }
    __syncthreads();

    // combine K-halves: w = rg + 2*kh -> out[rg] = scrF[rg] + scrF[rg+2]
#pragma unroll
    for (int i = 0; i < 8; ++i) {
        const int o  = t * 8 + i;          // 0 .. 2047
        const int r  = o >> 6;             // 0 .. 31
        const int c  = o & 63;
        const int g  = r >> 4;
        const int r15 = r & 15;
        yhat[(size_t)(rowbase + r) * CC + c] = scrF[g][r15][c] + scrF[g + 2][r15][c];
    }
}

// ---------------- fallback: proven fused kernel (round 2) ----------------
__global__ __launch_bounds__(512, 4)
void lp_main_fb(const float* __restrict__ bi, const float* __restrict__ mk,
                const float* __restrict__ labels,
                float* __restrict__ T, float* __restrict__ yhat)
{
    __shared__ unsigned short pT[4 * NN];
    const int t    = threadIdx.x;
    const int lane = t & 63;
    const int w    = t >> 6;
    const size_t rowbase = (size_t)blockIdx.x * 4 * NN;

    float pl[4];
    float h0 = 0.f, h1 = 0.f, h2 = 0.f, h3 = 0.f;
#pragma unroll
    for (int r = 0; r < 4; ++r) {
        const f32x4* b4 = (const f32x4*)(bi + rowbase + (size_t)r * NN);
        const f32x4* m4 = (const f32x4*)(mk + rowbase + (size_t)r * NN);
        float s = 0.f;
#pragma unroll
        for (int k = 0; k < 4; ++k) {
            const int j4 = t + 512 * k;
            f32x4 b = __builtin_nontemporal_load(b4 + j4);
            f32x4 m = __builtin_nontemporal_load(m4 + j4);
            f32x4 p = b * m;
            s += (p[0] + p[1]) + (p[2] + p[3]);
            if (r == 3 && k == 3) { h0 = p[0]; h1 = p[1]; h2 = p[2]; h3 = p[3]; }
            else {
                u16x4 q = { f2bf(p[0]), f2bf(p[1]), f2bf(p[2]), f2bf(p[3]) };
                *(u16x4*)(pT + r * NN + (j4 << 2)) = q;
            }
        }
        pl[r] = s;
    }
#pragma unroll
    for (int r = 0; r < 4; ++r) {
        float s = pl[r];
#pragma unroll
        for (int d = 32; d >= 1; d >>= 1) s += __shfl_xor(s, d, 64);
        pl[r] = s;
    }
    float* scr = (float*)(pT + 3 * NN + 8128);
    if (lane == 0) {
#pragma unroll
        for (int r = 0; r < 4; ++r) scr[w * 4 + r] = pl[r];
    }
    __syncthreads();
    float sc[4];
#pragma unroll
    for (int r = 0; r < 4; ++r) {
        float s = 0.f;
#pragma unroll
        for (int ww = 0; ww < 8; ++ww) s += scr[ww * 4 + r];
        sc[r] = 1.0f / fmaxf(s, 1e-12f);
    }
    __syncthreads();
    {
        const int j4 = t + 1536;
        u16x4 q = { f2bf(h0), f2bf(h1), f2bf(h2), f2bf(h3) };
        *(u16x4*)(pT + 3 * NN + (j4 << 2)) = q;
    }
    __syncthreads();
#pragma unroll
    for (int r = 0; r < 4; ++r) {
        f32x4* To = (f32x4*)(T + rowbase + (size_t)r * NN);
        const float s = sc[r];
#pragma unroll
        for (int k = 0; k < 4; ++k) {
            const int j4 = t + 512 * k;
            u16x4 q = *(const u16x4*)(pT + r * NN + (j4 << 2));
            f32x4 o = { b2f(q[0]) * s, b2f(q[1]) * s, b2f(q[2]) * s, b2f(q[3]) * s };
            __builtin_nontemporal_store(o, To + j4);
        }
    }
    const int c15    = lane & 15;
    const int rowsel = lane & 3;
    const int kgrp   = (lane >> 4) << 3;
    const int kbase  = w * (NN / 8);
    f32x4 acc0 = {0.f,0.f,0.f,0.f}, acc1 = acc0, acc2 = acc0, acc3 = acc0;
    const unsigned short* pA = pT + rowsel * NN + kbase + kgrp;
    for (int k0 = 0; k0 < NN / 8; k0 += 32) {
        short8 a = *(const short8*)(pA + k0);
        short8 q0, q1, q2, q3;
#pragma unroll
        for (int i = 0; i < 8; ++i) {
            const size_t kr = (size_t)(kbase + k0 + kgrp + i) * CC;
            q0[i] = (short)f2bf(labels[kr + c15]);
            q1[i] = (short)f2bf(labels[kr + 16 + c15]);
            q2[i] = (short)f2bf(labels[kr + 32 + c15]);
            q3[i] = (short)f2bf(labels[kr + 48 + c15]);
        }
        acc0 = __builtin_amdgcn_mfma_f32_16x16x32_bf16(a, q0, acc0, 0, 0, 0);
        acc1 = __builtin_amdgcn_mfma_f32_16x16x32_bf16(a, q1, acc1, 0, 0, 0);
        acc2 = __builtin_amdgcn_mfma_f32_16x16x32_bf16(a, q2, acc2, 0, 0, 0);
        acc3 = __builtin_amdgcn_mfma_f32_16x16x32_bf16(a, q3, acc3, 0, 0, 0);
    }
    __syncthreads();
    float* scrF = (float*)pT;
    if (lane < 16) {
#pragma unroll
        for (int i = 0; i < 4; ++i) {
            scrF[((w * 4 + 0) * 4 + i) * 16 + c15] = acc0[i];
            scrF[((w * 4 + 1) * 4 + i) * 16 + c15] = acc1[i];
            scrF[((w * 4 + 2) * 4 + i) * 16 + c15] = acc2[i];
            scrF[((w * 4 + 3) * 4 + i) * 16 + c15] = acc3[i];
        }
    }
    __syncthreads();
    if (t < 256) {
        const int r  = t >> 6;
        const int c  = t & 63;
        const int j  = c >> 4;
        const int cl = c & 15;
        float s = 0.f;
#pragma unroll
        for (int ww = 0; ww < 8; ++ww)
            s += scrF[((ww * 4 + j) * 4 + r) * 16 + cl];
        const float scl = (r == 0) ? sc[0] : (r == 1) ? sc[1] : (r == 2) ? sc[2] : sc[3];
        yhat[(size_t)blockIdx.x * 4 * CC + (size_t)r * CC + c] = s * scl;
    }
}

extern "C" void kernel_launch(void* const* d_in, const int* in_sizes, int n_in,
                              void* d_out, int out_size, void* d_ws, size_t ws_size,
                              hipStream_t stream) {
    (void)in_sizes; (void)n_in; (void)out_size;
    const float* labels = (const float*)d_in[2];
    const float* bi     = (const float*)d_in[4];
    const float* mask   = (const float*)d_in[5];
    float* T    = (float*)d_out;
    float* yhat = (float*)d_out + (size_t)NN * NN;

    const size_t labT_bytes = (size_t)NN * CC * 2;          // 1 MB
    const size_t P_bytes    = (size_t)NN * NN * 2;          // 128 MB

    if (ws_size >= labT_bytes + P_bytes) {
        unsigned short* labT = (unsigned short*)d_ws;
        unsigned short* P    = (unsigned short*)((char*)d_ws + labT_bytes);
        prep_labels<<<dim3(NN * CC / 4 / 256), dim3(256), 0, stream>>>(labels, labT);
        lp_stream<<<dim3(NN), dim3(256), 0, stream>>>(bi, mask, T, P);
        lp_gemm<<<dim3(NN / 32), dim3(256), 0, stream>>>(P, labT, yhat);
    } else {
        lp_main_fb<<<dim3(NN / 4), dim3(512), 0, stream>>>(bi, mask, labels, T, yhat);
    }
}